// Round 6
// baseline (77.119 us; speedup 1.0000x reference)
//
#include <hip/hip_runtime.h>
#include <math.h>

#define NB 16
#define NC 256
#define NH 64
#define NW 64
#define HALF 128
#define PLANE (NH*NW)   // 4096

#define NPG 32           // channel-pair groups (4 pairs each) -> partial slices

// ws float layout (small; cons partials live in d_out scratch)
#define WS_WW   0       // 256
#define WS_WH   256     // 256
#define WS_GH   512     // NB*NH = 1024
#define WS_GW   1536    // NB*NW = 1024
#define WS_ATT  2560    // NB*NH*NW = 65536
#define WS_TOTAL 68096

__device__ __forceinline__ float sum4(float4 v) { return (v.x+v.y)+(v.z+v.w); }

// blocks 0,1: zero gh/gw (512 float4). block 2: both channel softmaxes.
__global__ __launch_bounds__(256) void k_init(const float* __restrict__ dwh,
                                              const float* __restrict__ dww,
                                              float* __restrict__ ws) {
    const int t = threadIdx.x;
    if (blockIdx.x < 2) {
        float4 z = {0.f,0.f,0.f,0.f};
        reinterpret_cast<float4*>(ws + WS_GH)[blockIdx.x*256 + t] = z;
        return;
    }
    __shared__ float red[256];
    const float vh = dwh[t];
    const float vw = dww[t];

    red[t] = vw; __syncthreads();
    for (int s = 128; s > 0; s >>= 1) { if (t < s) red[t] = fmaxf(red[t], red[t+s]); __syncthreads(); }
    const float mw = red[0]; __syncthreads();
    const float ew = expf(vw - mw);
    red[t] = ew; __syncthreads();
    for (int s = 128; s > 0; s >>= 1) { if (t < s) red[t] += red[t+s]; __syncthreads(); }
    const float sw = red[0]; __syncthreads();
    ws[WS_WW + t] = ew / sw;

    red[t] = vh; __syncthreads();
    for (int s = 128; s > 0; s >>= 1) { if (t < s) red[t] = fmaxf(red[t], red[t+s]); __syncthreads(); }
    const float mh = red[0]; __syncthreads();
    const float eh = expf(vh - mh);
    red[t] = eh; __syncthreads();
    for (int s = 128; s > 0; s >>= 1) { if (t < s) red[t] += red[t+s]; __syncthreads(); }
    const float sh = red[0]; __syncthreads();
    ws[WS_WH + t] = eh / sh;
}

// Block = (b, 16-row stripe, group of 4 channel pairs). 2048 blocks.
// Wave = row-group (4 rows). Lane = fc(4b)<<2 | pl(2b): pair pl, float4-col fc.
// Cross-pair reductions via __shfl_xor(1,2); horizontal box taps via shfl(+-4).
// __launch_bounds__(256,4): allow ~128 VGPR so all 12 float4 loads stay in flight.
__global__ __launch_bounds__(256, 4) void k_reduce(const float* __restrict__ x,
                                                   float* __restrict__ ws,
                                                   float* __restrict__ part) {
    __shared__ float4 ldsc[4][16];   // 1 KB gw staging

    const int t    = threadIdx.x;
    const int rg   = t >> 6;        // wave id = row group 0..3
    const int lane = t & 63;
    const int pl   = lane & 3;      // channel pair lane
    const int fc   = lane >> 2;     // float4 col 0..15

    const int blk    = blockIdx.x;
    const int pg     = blk & 31;
    const int stripe = (blk >> 5) & 3;
    const int b      = blk >> 7;

    const int c1 = pg*4 + pl;
    const int c2 = c1 + HALF;
    const int r0 = stripe*16 + rg*4;     // first owned row

    const float ww1 = ws[WS_WW + c1], ww2 = ws[WS_WW + c2];
    const float wh1 = ws[WS_WH + c1], wh2 = ws[WS_WH + c2];

    const float* p1 = x + ((size_t)(b*NC + c1)) * PLANE;
    const float* p2 = x + ((size_t)(b*NC + c2)) * PLANE;

    // 12 independent float4 loads: rows r0-1 .. r0+4 (clamped), cols 4fc..4fc+3
    float4 a[6], bb[6];
    #pragma unroll
    for (int j = 0; j < 6; ++j) {
        int r = r0 - 1 + j;
        r = (r < 0) ? 0 : (r > 63 ? 63 : r);
        a[j]  = *(reinterpret_cast<const float4*>(p1 + r*NW) + fc);
        bb[j] = *(reinterpret_cast<const float4*>(p2 + r*NW) + fc);
    }

    // gh / gw contributions from owned rows (j=1..4 -> rows r0..r0+3)
    float ghrow[4];
    float4 colacc = {0.f,0.f,0.f,0.f};
    #pragma unroll
    for (int j = 1; j <= 4; ++j) {
        ghrow[j-1] = ww1*sum4(a[j]) + ww2*sum4(bb[j]);
        colacc.x += wh1*a[j].x + wh2*bb[j].x;
        colacc.y += wh1*a[j].y + wh2*bb[j].y;
        colacc.z += wh1*a[j].z + wh2*bb[j].z;
        colacc.w += wh1*a[j].w + wh2*bb[j].w;
    }

    // products, zero-pad masks at global top/bottom rows
    const float km0 = (r0 == 0)  ? 0.f : 1.f;
    const float km5 = (r0 == 60) ? 0.f : 1.f;
    float4 p[6];
    #pragma unroll
    for (int j = 0; j < 6; ++j) {
        p[j].x = a[j].x*bb[j].x; p[j].y = a[j].y*bb[j].y;
        p[j].z = a[j].z*bb[j].z; p[j].w = a[j].w*bb[j].w;
    }
    p[0].x *= km0; p[0].y *= km0; p[0].z *= km0; p[0].w *= km0;
    p[5].x *= km5; p[5].y *= km5; p[5].z *= km5; p[5].w *= km5;

    // vertical 3-tap in registers; horizontal 3-tap: neighbor col = lane +-4
    float4 c4[4];
    #pragma unroll
    for (int i = 0; i < 4; ++i) {
        float4 v;
        v.x = p[i].x + p[i+1].x + p[i+2].x;
        v.y = p[i].y + p[i+1].y + p[i+2].y;
        v.z = p[i].z + p[i+1].z + p[i+2].z;
        v.w = p[i].w + p[i+1].w + p[i+2].w;
        float L = __shfl_up(v.w, 4);
        float R = __shfl_down(v.x, 4);
        if (fc == 0)  L = 0.f;
        if (fc == 15) R = 0.f;
        c4[i].x = fabsf(L   + v.x + v.y);
        c4[i].y = fabsf(v.x + v.y + v.z);
        c4[i].z = fabsf(v.y + v.z + v.w);
        c4[i].w = fabsf(v.z + v.w + R);
    }

    // cons: reduce over the 4 pair-lanes (low 2 lane bits) via shfl_xor
    const float SC = 1.0f/(9.0f*128.0f);
    #pragma unroll
    for (int i = 0; i < 4; ++i) {
        c4[i].x += __shfl_xor(c4[i].x, 1); c4[i].x += __shfl_xor(c4[i].x, 2);
        c4[i].y += __shfl_xor(c4[i].y, 1); c4[i].y += __shfl_xor(c4[i].y, 2);
        c4[i].z += __shfl_xor(c4[i].z, 1); c4[i].z += __shfl_xor(c4[i].z, 2);
        c4[i].w += __shfl_xor(c4[i].w, 1); c4[i].w += __shfl_xor(c4[i].w, 2);
    }
    // slice layout: part[pg][b][h][w] pixel-linear within slice pg
    {
        float4* dst = reinterpret_cast<float4*>(part) + ((size_t)pg << 14) + (b << 10);
        if (pl == 0) {
            #pragma unroll
            for (int i = 0; i < 4; ++i) {
                float4 s = { c4[i].x*SC, c4[i].y*SC, c4[i].z*SC, c4[i].w*SC };
                dst[(r0 + i)*16 + fc] = s;
            }
        }
    }

    // gh: full-wave reduction (16 fc x 4 pl) per owned row
    float* gh = ws + WS_GH;
    float* gw = ws + WS_GW;
    #pragma unroll
    for (int k = 0; k < 4; ++k) {
        float s = ghrow[k];
        s += __shfl_xor(s, 1);  s += __shfl_xor(s, 2);
        s += __shfl_xor(s, 4);  s += __shfl_xor(s, 8);
        s += __shfl_xor(s, 16); s += __shfl_xor(s, 32);
        if (lane == 0) atomicAdd(&gh[b*NH + r0 + k], s * (1.0f/16384.0f));
    }

    // gw: reduce colacc over pairs (shfl) then over the 4 waves (tiny LDS)
    colacc.x += __shfl_xor(colacc.x, 1); colacc.x += __shfl_xor(colacc.x, 2);
    colacc.y += __shfl_xor(colacc.y, 1); colacc.y += __shfl_xor(colacc.y, 2);
    colacc.z += __shfl_xor(colacc.z, 1); colacc.z += __shfl_xor(colacc.z, 2);
    colacc.w += __shfl_xor(colacc.w, 1); colacc.w += __shfl_xor(colacc.w, 2);
    if (pl == 0) ldsc[rg][fc] = colacc;
    __syncthreads();
    if (t < 16) {
        float4 s0 = ldsc[0][t], s1 = ldsc[1][t], s2 = ldsc[2][t], s3 = ldsc[3][t];
        float4 s;
        s.x = (s0.x+s1.x)+(s2.x+s3.x);
        s.y = (s0.y+s1.y)+(s2.y+s3.y);
        s.z = (s0.z+s1.z)+(s2.z+s3.z);
        s.w = (s0.w+s1.w)+(s2.w+s3.w);
        float* g = &gw[b*NW + t*4];
        atomicAdd(g+0, s.x * (1.0f/16384.0f));
        atomicAdd(g+1, s.y * (1.0f/16384.0f));
        atomicAdd(g+2, s.z * (1.0f/16384.0f));
        atomicAdd(g+3, s.w * (1.0f/16384.0f));
    }
}

// attention map: sum 32 cons partials + gh + gw -> sigmoid, once per pixel.
// 256 blocks x 64 threads: one wave per block, spread across all CUs.
__global__ __launch_bounds__(64) void k_att(float* __restrict__ ws,
                                            const float* __restrict__ part,
                                            const float* __restrict__ pgw,
                                            const float* __restrict__ pgb) {
    const int u  = blockIdx.x*64 + threadIdx.x;   // float4-pixel 0..16383
    const int b  = u >> 10;
    const int h  = (u >> 4) & 63;
    const int w4 = u & 15;

    const float4* pp = reinterpret_cast<const float4*>(part);
    float4 s = {0.f,0.f,0.f,0.f};
    #pragma unroll
    for (int g = 0; g < NPG; ++g) {
        const float4 v = pp[(g << 14) + u];
        s.x += v.x; s.y += v.y; s.z += v.z; s.w += v.w;
    }
    const float ghv  = ws[WS_GH + b*NH + h];
    const float4 gwv = *reinterpret_cast<const float4*>(ws + WS_GW + b*NW + w4*4);
    const float gW = pgw[0], gB = pgb[0];

    float4 o;
    float z;
    z = gW*(ghv+gwv.x)*(1.f - fminf(fmaxf(s.x,0.f),1.f)) + gB; o.x = 1.f/(1.f+expf(-z));
    z = gW*(ghv+gwv.y)*(1.f - fminf(fmaxf(s.y,0.f),1.f)) + gB; o.y = 1.f/(1.f+expf(-z));
    z = gW*(ghv+gwv.z)*(1.f - fminf(fmaxf(s.z,0.f),1.f)) + gB; o.z = 1.f/(1.f+expf(-z));
    z = gW*(ghv+gwv.w)*(1.f - fminf(fmaxf(s.w,0.f),1.f)) + gB; o.w = 1.f/(1.f+expf(-z));
    reinterpret_cast<float4*>(ws + WS_ATT)[u] = o;
}

__global__ __launch_bounds__(256) void k_apply(const float* __restrict__ x,
                                               const float* __restrict__ ws,
                                               float* __restrict__ out) {
    const float* att = ws + WS_ATT;
    const int total4 = NB*NC*NH*NW/4;   // 4,194,304
    const int stride = gridDim.x * blockDim.x;
    for (int i = blockIdx.x*blockDim.x + threadIdx.x; i < total4; i += stride) {
        const int w4 = i & 15;
        const int h  = (i >> 4) & 63;
        const int b  = i >> 18;
        const float4 xv = reinterpret_cast<const float4*>(x)[i];
        const float4 av = reinterpret_cast<const float4*>(att)[(b << 10) + (h << 4) + w4];
        float4 o;
        o.x = xv.x*av.x; o.y = xv.y*av.y; o.z = xv.z*av.z; o.w = xv.w*av.w;
        reinterpret_cast<float4*>(out)[i] = o;
    }
}

extern "C" void kernel_launch(void* const* d_in, const int* in_sizes, int n_in,
                              void* d_out, int out_size, void* d_ws, size_t ws_size,
                              hipStream_t stream) {
    const float* x   = (const float*)d_in[0];
    const float* dwh = (const float*)d_in[1];
    const float* dww = (const float*)d_in[2];
    const float* pgw = (const float*)d_in[3];
    const float* pgb = (const float*)d_in[4];
    float* out = (float*)d_out;
    float* ws  = (float*)d_ws;
    // d_out doubles as scratch for cons partials (8 MB): written by k_reduce,
    // consumed by k_att, then fully overwritten by k_apply.
    float* part = out;

    k_init<<<3, 256, 0, stream>>>(dwh, dww, ws);
    k_reduce<<<NB*4*NPG, 256, 0, stream>>>(x, ws, part);
    k_att<<<256, 64, 0, stream>>>(ws, part, pgw, pgb);
    k_apply<<<2048, 256, 0, stream>>>(x, ws, out);
}